// Round 1
// baseline (1276.012 us; speedup 1.0000x reference)
//
#include <hip/hip_runtime.h>
#include <cstddef>
#include <cstdint>

// Problem constants (fixed by setup_inputs)
#define NB 8
#define LQ 8192
#define DMODEL 256
#define NHD 8
#define NLV 4
#define NPT 4
#define DH 32
#define LEN_IN 19560          // 92*160 + 46*80 + 23*40 + 12*20
#define NQ (NB * LQ)          // 65536
#define MV (NB * LEN_IN)      // 156480

// ---------------------------------------------------------------------------
// Generic fp32 GEMM, C[M,N] = A[M,K=256] @ B[256,N] + bias[N]
// Exact tiling: M % 64 == 0, N % 64 == 0. Block = 256 threads, 64x64 tile,
// 4x4 microtile per thread.
// ---------------------------------------------------------------------------
__global__ __launch_bounds__(256) void gemm_bias_k256(
    const float* __restrict__ A, const float* __restrict__ Bm,
    const float* __restrict__ bias, float* __restrict__ C, int N) {
  constexpr int K = 256;
  // pad rows to 68 floats: keeps 16B alignment for float4 LDS access,
  // breaks power-of-2 bank stride
  __shared__ float As[16][68];  // [k][m]
  __shared__ float Bs[16][68];  // [k][n]

  const int bm = blockIdx.y * 64;
  const int bn = blockIdx.x * 64;
  const int tid = threadIdx.x;
  const int tx = tid & 15;       // n-subtile
  const int ty = tid >> 4;       // m-subtile
  const int am = tid >> 2;       // 0..63 : m row to load
  const int ak = (tid & 3) << 2; // 0,4,8,12 : k offset to load
  const int bk = tid >> 4;       // 0..15 : k row to load
  const int bn4 = (tid & 15) << 2; // n offset to load

  float acc[4][4] = {};

  for (int k0 = 0; k0 < K; k0 += 16) {
    float4 av = *(const float4*)(A + (size_t)(bm + am) * K + (k0 + ak));
    float4 bv = *(const float4*)(Bm + (size_t)(k0 + bk) * N + (bn + bn4));
    __syncthreads();  // previous iteration's compute done before overwrite
    As[ak + 0][am] = av.x;
    As[ak + 1][am] = av.y;
    As[ak + 2][am] = av.z;
    As[ak + 3][am] = av.w;
    *(float4*)&Bs[bk][bn4] = bv;
    __syncthreads();
#pragma unroll
    for (int kk = 0; kk < 16; ++kk) {
      float4 a4 = *(const float4*)&As[kk][ty << 2];
      float4 b4 = *(const float4*)&Bs[kk][tx << 2];
      const float a[4] = {a4.x, a4.y, a4.z, a4.w};
      const float b[4] = {b4.x, b4.y, b4.z, b4.w};
#pragma unroll
      for (int i = 0; i < 4; ++i)
#pragma unroll
        for (int j = 0; j < 4; ++j) acc[i][j] += a[i] * b[j];
    }
  }

  float4 bv = *(const float4*)(bias + bn + (tx << 2));
  const float bb[4] = {bv.x, bv.y, bv.z, bv.w};
#pragma unroll
  for (int i = 0; i < 4; ++i) {
    float4 o;
    o.x = acc[i][0] + bb[0];
    o.y = acc[i][1] + bb[1];
    o.z = acc[i][2] + bb[2];
    o.w = acc[i][3] + bb[3];
    *(float4*)(C + (size_t)(bm + (ty << 2) + i) * N + bn + (tx << 2)) = o;
  }
}

// ---------------------------------------------------------------------------
// Softmax over contiguous groups of 16 (in-place). One thread per group.
// ---------------------------------------------------------------------------
__global__ __launch_bounds__(256) void softmax16(float* __restrict__ a) {
  const int g = blockIdx.x * blockDim.x + threadIdx.x;  // exactly NQ*NHD threads
  float* p = a + (size_t)g * 16;
  float v[16];
  float m = -1e30f;
#pragma unroll
  for (int i = 0; i < 16; ++i) {
    v[i] = p[i];
    m = fmaxf(m, v[i]);
  }
  float s = 0.f;
#pragma unroll
  for (int i = 0; i < 16; ++i) {
    v[i] = expf(v[i] - m);
    s += v[i];
  }
  const float inv = 1.f / s;
#pragma unroll
  for (int i = 0; i < 16; ++i) p[i] = v[i] * inv;
}

// ---------------------------------------------------------------------------
// Bilinear sampling + attention-weighted accumulation.
// One block per query; 256 threads = 8 heads x 32 channels.
// ---------------------------------------------------------------------------
__device__ __forceinline__ float tap(const float* __restrict__ vlev, int xi,
                                     int yi, int H, int W, int ch) {
  const bool valid = (xi >= 0) & (xi < W) & (yi >= 0) & (yi < H);
  const int xc = min(max(xi, 0), W - 1);
  const int yc = min(max(yi, 0), H - 1);
  const float s = vlev[(size_t)(yc * W + xc) * DMODEL + ch];
  return valid ? s : 0.f;
}

__global__ __launch_bounds__(256) void msda_sample(
    const float* __restrict__ refp,   // (NB, LQ, NLV, 2)
    const float* __restrict__ attnw,  // (NQ, 128) softmaxed
    const float* __restrict__ off,    // (NQ, 256)
    const float* __restrict__ value,  // (NB, LEN_IN, 256)
    float* __restrict__ mid) {        // (NQ, 256)
  const int q = blockIdx.x;  // 0..NQ-1
  const int tid = threadIdx.x;
  const int h = tid >> 5;
  const int dh = tid & 31;
  const int ch = (h << 5) + dh;  // == tid

  __shared__ float s_attn[128];
  __shared__ float s_off[256];
  __shared__ float s_ref[8];

  s_off[tid] = off[(size_t)q * 256 + tid];
  if (tid < 128) s_attn[tid] = attnw[(size_t)q * 128 + tid];
  if (tid < 8) s_ref[tid] = refp[(size_t)q * 8 + tid];
  __syncthreads();

  const int b = q >> 13;  // q / LQ
  const float* vbase = value + (size_t)b * LEN_IN * DMODEL;

  constexpr int Hs[4] = {92, 46, 23, 12};
  constexpr int Ws[4] = {160, 80, 40, 20};
  constexpr int S0[4] = {0, 14720, 18400, 19320};

  float acc = 0.f;
#pragma unroll
  for (int l = 0; l < NLV; ++l) {
    const int Hl = Hs[l], Wl = Ws[l];
    const float rx = s_ref[l * 2 + 0];
    const float ry = s_ref[l * 2 + 1];
    const float* vlev = vbase + (size_t)S0[l] * DMODEL;
#pragma unroll
    for (int p = 0; p < NPT; ++p) {
      const int lp = (h * NLV + l) * NPT + p;
      const float ox = s_off[lp * 2 + 0];
      const float oy = s_off[lp * 2 + 1];
      const float w = s_attn[lp];
      // x = (ref_x + off_x/W) * W - 0.5 == ref_x*W + off_x - 0.5
      const float x = rx * (float)Wl + ox - 0.5f;
      const float y = ry * (float)Hl + oy - 0.5f;
      const float xf = floorf(x);
      const float yf = floorf(y);
      const float wx = x - xf;
      const float wy = y - yf;
      const int x0 = (int)xf;
      const int y0 = (int)yf;
      const float v00 = tap(vlev, x0, y0, Hl, Wl, ch);
      const float v10 = tap(vlev, x0 + 1, y0, Hl, Wl, ch);
      const float v01 = tap(vlev, x0, y0 + 1, Hl, Wl, ch);
      const float v11 = tap(vlev, x0 + 1, y0 + 1, Hl, Wl, ch);
      const float bil = (1.f - wx) * (1.f - wy) * v00 + wx * (1.f - wy) * v10 +
                        (1.f - wx) * wy * v01 + wx * wy * v11;
      acc += w * bil;
    }
  }
  mid[(size_t)q * 256 + tid] = acc;
}

// ---------------------------------------------------------------------------
// Launch
// ---------------------------------------------------------------------------
extern "C" void kernel_launch(void* const* d_in, const int* in_sizes, int n_in,
                              void* d_out, int out_size, void* d_ws,
                              size_t ws_size, hipStream_t stream) {
  const float* query = (const float*)d_in[0];
  const float* refp = (const float*)d_in[1];
  const float* inflat = (const float*)d_in[2];
  // d_in[3] spatial shapes, d_in[4] level starts: compile-time constants
  const float* W_off = (const float*)d_in[5];
  const float* b_off = (const float*)d_in[6];
  const float* W_attn = (const float*)d_in[7];
  const float* b_attn = (const float*)d_in[8];
  const float* W_val = (const float*)d_in[9];
  const float* b_val = (const float*)d_in[10];
  const float* W_out = (const float*)d_in[11];
  const float* b_out = (const float*)d_in[12];
  float* out = (float*)d_out;

  // Workspace layout (fp32):
  //   value : MV*256   = 160,235,520 B
  //   attn  : NQ*128   =  33,554,432 B
  //   off   : NQ*256   =  67,108,864 B
  //   mid   : NQ*256   =  67,108,864 B   total 328,007,680 B
  char* ws = (char*)d_ws;
  float* v_ws = (float*)(ws);
  float* attn_ws = (float*)(ws + 160235520ULL);
  float* off_ws = (float*)(ws + 193789952ULL);
  float* mid_ws = (float*)(ws + 260898816ULL);

  // 1. value = input_flatten @ W_val + b_val          (156480 x 256)
  gemm_bias_k256<<<dim3(256 / 64, MV / 64), 256, 0, stream>>>(inflat, W_val,
                                                              b_val, v_ws, 256);
  // 2. attn logits = query @ W_attn + b_attn          (65536 x 128)
  gemm_bias_k256<<<dim3(128 / 64, NQ / 64), 256, 0, stream>>>(
      query, W_attn, b_attn, attn_ws, 128);
  // 3. offsets = query @ W_off + b_off                (65536 x 256)
  gemm_bias_k256<<<dim3(256 / 64, NQ / 64), 256, 0, stream>>>(
      query, W_off, b_off, off_ws, 256);
  // 4. softmax over groups of 16 (in place): NQ*NHD = 524288 groups
  softmax16<<<(NQ * NHD) / 256, 256, 0, stream>>>(attn_ws);
  // 5. bilinear sampling + weighted sum -> mid        (65536 x 256)
  msda_sample<<<NQ, 256, 0, stream>>>(refp, attn_ws, off_ws, v_ws, mid_ws);
  // 6. out = mid @ W_out + b_out                      (65536 x 256)
  gemm_bias_k256<<<dim3(256 / 64, NQ / 64), 256, 0, stream>>>(mid_ws, W_out,
                                                              b_out, out, 256);
}